// Round 1
// 592.988 us; speedup vs baseline: 1.0725x; 1.0725x over previous
//
#include <hip/hip_runtime.h>
#include <hip/hip_bf16.h>
#include <cstdint>
#include <cstddef>

// Problem constants (from reference setup_inputs): B=8, S=4096, IN=OUT=2048
#define M_TOT 32768   // B*S
#define N_OUT 2048
#define K_IN  2048

typedef int v4i __attribute__((ext_vector_type(4)));

// async global->LDS, 16B per lane; lds base must be wave-uniform
__device__ __forceinline__ void gload16(const int8_t* g, int8_t* l) {
  __builtin_amdgcn_global_load_lds(
      (const __attribute__((address_space(1))) void*)g,
      (__attribute__((address_space(3))) void*)l, 16, 0, 0);
}

// ---------------------------------------------------------------------------
// Kernel 1/2: per-row smooth + quantize, exact fp16 reference semantics.
// (unchanged from previous passing version)
// ---------------------------------------------------------------------------
__global__ __launch_bounds__(256) void quant_rows_kernel(
    const float* __restrict__ in,
    const float* __restrict__ scales,
    int8_t* __restrict__ q, float* __restrict__ rmax, int mul_mode)
{
  const int row = blockIdx.x;
  const int tid = threadIdx.x;
  const size_t base = (size_t)row * K_IN + tid * 8;
  const float4 xv0 = *(const float4*)(in + base);
  const float4 xv1 = *(const float4*)(in + base + 4);
  const float4 sv0 = *(const float4*)(scales + tid * 8);
  const float4 sv1 = *(const float4*)(scales + tid * 8 + 4);
  const float xf[8] = {xv0.x, xv0.y, xv0.z, xv0.w, xv1.x, xv1.y, xv1.z, xv1.w};
  const float sf[8] = {sv0.x, sv0.y, sv0.z, sv0.w, sv1.x, sv1.y, sv1.z, sv1.w};
  _Float16 xs[8];
  float amax = 0.f;
#pragma unroll
  for (int i = 0; i < 8; ++i) {
    const _Float16 hx = (_Float16)xf[i];
    const _Float16 hs = (_Float16)sf[i];
    xs[i] = mul_mode ? (_Float16)(hx * hs) : (_Float16)(hx / hs);  // fp16 RNE
    amax = fmaxf(amax, fabsf((float)xs[i]));
  }
#pragma unroll
  for (int off = 32; off; off >>= 1) amax = fmaxf(amax, __shfl_down(amax, off));
  __shared__ float red[4];
  const int wid = tid >> 6, lane = tid & 63;
  if (lane == 0) red[wid] = amax;
  __syncthreads();
  amax = fmaxf(fmaxf(red[0], red[1]), fmaxf(red[2], red[3]));
  _Float16 hqm = (_Float16)amax / (_Float16)127.0f;
  if (tid == 0) rmax[row] = (float)hqm;
  if (hqm == (_Float16)0.f) hqm = (_Float16)1.0f;
  int8_t qb[8];
#pragma unroll
  for (int i = 0; i < 8; ++i) {
    const float qf = (float)(_Float16)(xs[i] / hqm);
    qb[i] = (int8_t)(int)qf;
  }
  unsigned long long pk;
  __builtin_memcpy(&pk, qb, 8);
  *(unsigned long long*)(q + (size_t)row * K_IN + tid * 8) = pk;
}

// ---------------------------------------------------------------------------
// Kernel 3: int8 GEMM, 256x256 tile, 8-phase counted-vmcnt schedule (T2+T3+
// T4+T5 port of the m201 template, adapted to int8 BK=128).
//
// Geometry: 512 thr = 8 waves (2M x 4N); per-wave output 128x64;
// mfma_i32_16x16x64_i8, acc[8][4] (128 VGPR).
// LDS ring: 8 slots x 16KB = 128KB. Granule g (g=0..63): tile t=g>>2,
// type: g&1 ? B : A, k-half (g>>1)&1. Granule = 256 rows x 64B, slot g%8.
// Stage stream: phase n stages h(n+4) (2 x global_load_lds w=16/thread);
// steady wait = vmcnt(8) -> h(n) landed before barrier; reads at phase n
// touch h(n-1),h(n). Invariants (checked): read slots / landing slots /
// stage slots disjoint mod 8 between consecutive barriers; tail drains
// vmcnt 8 -> 0 only in the last 2 of 16 K-tiles.
//
// Swizzle (T2, both-sides): 16B chunk c of row r lives at chunk c^((r>>1)&3).
// global_load_lds dest stays linear (base+lane*16); the permutation is
// applied to the per-lane GLOBAL source (involution), and to the ds_read
// offset. 16-lane read phases span all 8 bank-groups (2 lanes/bank = free).
// ---------------------------------------------------------------------------
__global__ __launch_bounds__(512, 2) void gemm_i8_kernel(
    const int8_t* __restrict__ Aq, const int8_t* __restrict__ Bq,
    const float* __restrict__ Am, const float* __restrict__ Bm,
    const float* __restrict__ bias, float* __restrict__ out)
{
  __shared__ __align__(16) int8_t lds[8 * 16384];   // 128 KiB ring
  const int tid = threadIdx.x;
  const int w = tid >> 6, lane = tid & 63;
  const int wm = w >> 2, wn = w & 3;                // 2 x 4 wave grid
  // XCD affinity: round-robin dispatch puts bid%8 on one XCD -> each XCD
  // owns one 256-wide N-panel (B slice 512KB, L2-resident); A-panels are
  // swept in lockstep across XCDs and served by L3 (xq = 64MB << 256MB).
  const int bx = blockIdx.x & 7;                    // N-tile
  const int by = blockIdx.x >> 3;                   // M-tile
  const long bm = (long)by * 256;
  const int  bn = bx * 256;

  // --- staging source (per thread), inverse-swizzled chunk ---
  const int schunk = ((lane & 3) ^ ((lane >> 3) & 3)) * 16;
  const int srow = w * 16 + (lane >> 2);            // + j*128 for 2nd load
  const int8_t* gA = Aq + (bm + srow) * (long)K_IN + schunk;
  const int8_t* gB = Bq + ((long)(bn + srow)) * K_IN + schunk;

  // --- fragment read offsets (swizzled) ---
  const int fr = lane & 15, fq = lane >> 4;
  const int pc = (fq ^ ((fr >> 1) & 3)) * 16;       // physical 16B chunk
  const int aoff = (wm * 128 + fr) * 64 + pc;       // + (mh*64+mi*16)*64
  const int boff = (wn * 64  + fr) * 64 + pc;       // + ni*16*64

  v4i acc[8][4] = {};
  v4i bfr[4];                                       // B frags cached across m-halves

#define STAGE(G) do {                                                         \
    const int g_ = (G);                                                       \
    const long koff_ = (long)((g_ >> 2) * 128 + ((g_ >> 1) & 1) * 64);        \
    int8_t* const ld_ = lds + (g_ & 7) * 16384 + w * 1024;                    \
    const int8_t* const gp_ = (g_ & 1) ? gB : gA;                             \
    gload16(gp_ + koff_,                  ld_);                               \
    gload16(gp_ + koff_ + 128L * K_IN,    ld_ + 8192);                        \
  } while (0)

#define VMCNT(N) asm volatile("s_waitcnt vmcnt(" #N ")" ::: "memory")
#define BAR() do { asm volatile("" ::: "memory");                             \
                   __builtin_amdgcn_s_barrier();                              \
                   asm volatile("" ::: "memory"); } while (0)

  // compute quadrant (T, KH, MH): 16 MFMA; B frags loaded on MH==0, reused on MH==1
#define QUAD(T, KH, MH) do {                                                  \
    const int sa_ = (((T) & 1) * 4 + (KH) * 2) * 16384;                       \
    if ((MH) == 0) {                                                          \
      _Pragma("unroll")                                                       \
      for (int ni = 0; ni < 4; ++ni)                                          \
        bfr[ni] = *(const v4i*)(lds + sa_ + 16384 + boff + ni * 1024);        \
    }                                                                         \
    v4i afr[4];                                                               \
    _Pragma("unroll")                                                         \
    for (int mi = 0; mi < 4; ++mi)                                            \
      afr[mi] = *(const v4i*)(lds + sa_ + aoff + ((MH) * 64 + mi * 16) * 64); \
    __builtin_amdgcn_s_setprio(1);                                            \
    _Pragma("unroll")                                                         \
    for (int mi = 0; mi < 4; ++mi)                                            \
      _Pragma("unroll")                                                       \
      for (int ni = 0; ni < 4; ++ni)                                          \
        acc[(MH) * 4 + mi][ni] = __builtin_amdgcn_mfma_i32_16x16x64_i8(       \
            afr[mi], bfr[ni], acc[(MH) * 4 + mi][ni], 0, 0, 0);               \
    __builtin_amdgcn_s_setprio(0);                                            \
  } while (0)

  // prologue: h0..h3, then phase 0 stages h4; vmcnt(8) retires h0.
  STAGE(0); STAGE(1); STAGE(2); STAGE(3);
  STAGE(4); VMCNT(8); BAR();

#pragma unroll 2
  for (int t = 0; t < 14; ++t) {
    STAGE(4 * t + 5); VMCNT(8); BAR(); QUAD(t, 0, 0);
    STAGE(4 * t + 6); VMCNT(8); BAR(); QUAD(t, 0, 1);
    STAGE(4 * t + 7); VMCNT(8); BAR(); QUAD(t, 1, 0);
    STAGE(4 * t + 8); VMCNT(8); BAR(); QUAD(t, 1, 1);
  }
  // tile 14: last three granules staged; then drain.
  STAGE(61); VMCNT(8); BAR(); QUAD(14, 0, 0);
  STAGE(62); VMCNT(8); BAR(); QUAD(14, 0, 1);
  STAGE(63); VMCNT(8); BAR(); QUAD(14, 1, 0);
  VMCNT(0);  BAR();
  QUAD(14, 1, 1);
  // tile 15: everything landed; no LDS writes remain -> no barriers needed.
  QUAD(15, 0, 0); QUAD(15, 0, 1); QUAD(15, 1, 0); QUAD(15, 1, 1);

#undef STAGE
#undef VMCNT
#undef BAR
#undef QUAD

  // epilogue; C/D layout: col = lane&15, row = (lane>>4)*4 + reg [m89-verified]
  const long cm0 = bm + wm * 128;
  const int  cn0 = bn + wn * 64;
  float amv[8][4];
#pragma unroll
  for (int mi = 0; mi < 8; ++mi)
#pragma unroll
    for (int r = 0; r < 4; ++r)
      amv[mi][r] = Am[cm0 + mi * 16 + fq * 4 + r];
#pragma unroll
  for (int ni = 0; ni < 4; ++ni) {
    const int col = cn0 + ni * 16 + fr;
    const float wmv = Bm[col];
    const _Float16 bsv = (_Float16)bias[col];
#pragma unroll
    for (int mi = 0; mi < 8; ++mi) {
#pragma unroll
      for (int r = 0; r < 4; ++r) {
        const long row = cm0 + mi * 16 + fq * 4 + r;
        // mx = fp16(x_max * w_max), promoted to fp32
        const float mx = (float)(_Float16)((_Float16)amv[mi][r] * (_Float16)wmv);
        // res = fp16(res_q_f32 * mx); res = res + bias (fp16 add)
        const _Float16 resh = (_Float16)((float)acc[mi][ni][r] * mx);
        out[row * N_OUT + col] = (float)(_Float16)(resh + bsv);
      }
    }
  }
}

extern "C" void kernel_launch(void* const* d_in, const int* in_sizes, int n_in,
                              void* d_out, int out_size, void* d_ws, size_t ws_size,
                              hipStream_t stream) {
  const float* x      = (const float*)d_in[0];  // [8,4096,2048] fp32 (fp16 values)
  const float* ori_w  = (const float*)d_in[1];  // [2048,2048]
  const float* scales = (const float*)d_in[2];  // [2048]
  const float* bias   = (const float*)d_in[3];  // [2048]
  float* out = (float*)d_out;                   // [8,4096,2048] fp32

  // workspace layout: xq (64MB) | wq (4MB) | xm (128KB fp32) | wm (8KB fp32)
  int8_t* xq = (int8_t*)d_ws;
  int8_t* wq = xq + (size_t)M_TOT * K_IN;
  float*  xm = (float*)(wq + (size_t)N_OUT * K_IN);
  float*  wmx = xm + M_TOT;

  quant_rows_kernel<<<M_TOT, 256, 0, stream>>>(x, scales, xq, xm, 0);
  quant_rows_kernel<<<N_OUT, 256, 0, stream>>>(ori_w, scales, wq, wmx, 1);

  // 1024 blocks: bid&7 = N-tile (XCD-affine), bid>>3 = M-tile
  gemm_i8_kernel<<<dim3(1024), 512, 0, stream>>>(xq, wq, xm, wmx, bias, out);
}

// Round 2
// 587.847 us; speedup vs baseline: 1.0819x; 1.0087x over previous
//
#include <hip/hip_runtime.h>
#include <hip/hip_bf16.h>
#include <cstdint>
#include <cstddef>

// Problem constants (from reference setup_inputs): B=8, S=4096, IN=OUT=2048
#define M_TOT 32768   // B*S
#define N_OUT 2048
#define K_IN  2048

typedef int   v4i __attribute__((ext_vector_type(4)));
typedef float v4f __attribute__((ext_vector_type(4)));

// async global->LDS, 16B per lane; lds base must be wave-uniform
__device__ __forceinline__ void gload16(const int8_t* g, int8_t* l) {
  __builtin_amdgcn_global_load_lds(
      (const __attribute__((address_space(1))) void*)g,
      (__attribute__((address_space(3))) void*)l, 16, 0, 0);
}

// ---------------------------------------------------------------------------
// Quant: one WAVE per row (2048 elems = 32/lane), shfl-only reduction.
// Replaces the 1-block-per-row version (~90us for x): no LDS round trip, no
// __syncthreads, 4 rows per 256-thr block, grid-stride. x is read exactly
// once -> nontemporal loads keep L3 clean for the gemm's A panels.
// Exact fp16 reference semantics preserved:
//   mode 0: xs = fp16(x / s);  mode 1: xs = fp16(w * s)
//   rmax = fp16(max|xs|) / fp16(127);  q = trunc(fp16(xs / rmax)) as int8
// ---------------------------------------------------------------------------
__global__ __launch_bounds__(256) void quant_rows_wave(
    const float* __restrict__ in,
    const float* __restrict__ scales,
    int8_t* __restrict__ q, float* __restrict__ rmax,
    int nrows, int mul_mode)
{
  const int wib = threadIdx.x >> 6, lane = threadIdx.x & 63;
  for (int row = blockIdx.x * 4 + wib; row < nrows; row += gridDim.x * 4) {
    const float* rp = in + (size_t)row * K_IN;
    _Float16 xs[32];
    float amax = 0.f;
#pragma unroll
    for (int c = 0; c < 8; ++c) {
      const int off = c * 256 + lane * 4;
      const v4f xv = __builtin_nontemporal_load((const v4f*)(rp + off));
      const v4f sv = *(const v4f*)(scales + off);
#pragma unroll
      for (int j = 0; j < 4; ++j) {
        const _Float16 hx = (_Float16)xv[j];
        const _Float16 hs = (_Float16)sv[j];
        const _Float16 v = mul_mode ? (_Float16)(hx * hs) : (_Float16)(hx / hs);
        xs[c * 4 + j] = v;
        amax = fmaxf(amax, fabsf((float)v));
      }
    }
    // full-wave butterfly max (exact; max is commutative/associative)
#pragma unroll
    for (int off = 32; off; off >>= 1) amax = fmaxf(amax, __shfl_xor(amax, off));
    _Float16 hqm = (_Float16)amax / (_Float16)127.0f;   // fp16 division
    if (lane == 0) rmax[row] = (float)hqm;
    if (hqm == (_Float16)0.f) hqm = (_Float16)1.0f;     // defensive 0/0 guard
#pragma unroll
    for (int c = 0; c < 8; ++c) {
      int8_t qb[4];
#pragma unroll
      for (int j = 0; j < 4; ++j) {
        const float qf = (float)(_Float16)(xs[c * 4 + j] / hqm);  // fp16 div
        qb[j] = (int8_t)(int)qf;                                  // trunc
      }
      int pk;
      __builtin_memcpy(&pk, qb, 4);
      *(int*)(q + (size_t)row * K_IN + c * 256 + lane * 4) = pk;
    }
  }
}

// ---------------------------------------------------------------------------
// Kernel 3: int8 GEMM, 256x256 tile, TWO-BARRIER 8-phase schedule (faithful
// m201 structure): per phase {READS(quad n); STAGE(n+6); VMCNT(8); BAR;
// [lgkm drain by compiler]; setprio; 16 MFMA; setprio; BAR}.
//
// vs R1's single-barrier variant: ds_reads now issue in the R-region BEFORE
// the barrier, so the CU-wide LDS read burst (~384cyc) hides under the vmcnt
// wait + barrier arrival instead of serializing ahead of the MFMA cluster.
//
// Pipeline: D=6 (stage granule n+6 at phase n), F=4 in flight (VMCNT(8)).
// Guarantee at phase n's barriers: G(n) = n+2 landed; reads at R_{n+1} touch
// at most granule n+2 -> just-in-time. Slot map (8 slots, granule g -> g&7):
//   reads window [n-2, n+1] | landings {n+3..n+6} | stage writes (n-2)&7.
// Stage-slot reuse is safe: granule n-2's last reads are lgkm-drained before
// each wave's MFMA in M_{n-1}, hence before BAR_b(n-1) < any STAGE in R_n.
// Tail: stages end at granule 63 (phase 57); drain VMCNT 4 -> 0 at phases
// 59/61; phases 62-63 barrier-free (no landings remain).
//
// Swizzle (T2, both sides): 16B chunk c of row r stored at chunk c^((r>>1)&3);
// applied to per-lane GLOBAL source at staging (global_load_lds dest must be
// linear) and to the ds_read offset. Bank-conflict-free (measured 0).
// ---------------------------------------------------------------------------
__global__ __launch_bounds__(512, 2) void gemm_i8_kernel(
    const int8_t* __restrict__ Aq, const int8_t* __restrict__ Bq,
    const float* __restrict__ Am, const float* __restrict__ Bm,
    const float* __restrict__ bias, float* __restrict__ out)
{
  __shared__ __align__(16) int8_t lds[8 * 16384];   // 128 KiB ring
  const int tid = threadIdx.x;
  const int w = tid >> 6, lane = tid & 63;
  const int wm = w >> 2, wn = w & 3;                // 2 x 4 wave grid
  // XCD affinity: bid%8 = XCD -> each XCD owns one 256-wide N-panel (B slice
  // 512KB L2-resident); all XCDs sweep the same M-panels (A served by L3).
  const int bx = blockIdx.x & 7;                    // N-tile
  const int by = blockIdx.x >> 3;                   // M-tile
  const long bm = (long)by * 256;
  const int  bn = bx * 256;

  // --- staging source (per thread), inverse-swizzled chunk ---
  const int schunk = ((lane & 3) ^ ((lane >> 3) & 3)) * 16;
  const int srow = w * 16 + (lane >> 2);            // + 128 for 2nd load
  const int8_t* gA = Aq + (bm + srow) * (long)K_IN + schunk;
  const int8_t* gB = Bq + ((long)(bn + srow)) * K_IN + schunk;

  // --- fragment read offsets (swizzled) ---
  const int fr = lane & 15, fq = lane >> 4;
  const int pc = (fq ^ ((fr >> 1) & 3)) * 16;       // physical 16B chunk
  const int aoff = (wm * 128 + fr) * 64 + pc;       // + (mh*64+mi*16)*64
  const int boff = (wn * 64  + fr) * 64 + pc;       // + ni*16*64

  v4i acc[8][4] = {};
  v4i afr[4], bfr[4];   // bfr cached across the two m-half phases of a (T,KH)

  // granule g: tile t=g>>2; g&1: 0=A,1=B; k-half=(g>>1)&1; slot g&7.
#define STAGE(G) do {                                                         \
    const int g_ = (G);                                                       \
    const long koff_ = (long)((g_ >> 2) * 128 + ((g_ >> 1) & 1) * 64);        \
    int8_t* const ld_ = lds + (g_ & 7) * 16384 + w * 1024;                    \
    const int8_t* const gp_ = (g_ & 1) ? gB : gA;                             \
    gload16(gp_ + koff_,                  ld_);                               \
    gload16(gp_ + koff_ + 128L * K_IN,    ld_ + 8192);                        \
  } while (0)

#define VMCNT(N) asm volatile("s_waitcnt vmcnt(" #N ")" ::: "memory")
#define BAR() do { asm volatile("" ::: "memory");                             \
                   __builtin_amdgcn_s_barrier();                              \
                   asm volatile("" ::: "memory"); } while (0)

  // R-region ds_reads for quad (T,KH,MH); B frags only on MH==0 (cached).
#define READS(T, KH, MH) do {                                                 \
    const int sa_ = (((T) & 1) * 4 + (KH) * 2) * 16384;                       \
    if ((MH) == 0) {                                                          \
      _Pragma("unroll")                                                       \
      for (int ni = 0; ni < 4; ++ni)                                          \
        bfr[ni] = *(const v4i*)(lds + sa_ + 16384 + boff + ni * 1024);        \
    }                                                                         \
    _Pragma("unroll")                                                         \
    for (int mi = 0; mi < 4; ++mi)                                            \
      afr[mi] = *(const v4i*)(lds + sa_ + aoff + ((MH) * 64 + mi * 16) * 64); \
  } while (0)

#define MFMA16(MH) do {                                                       \
    __builtin_amdgcn_s_setprio(1);                                            \
    _Pragma("unroll")                                                         \
    for (int mi = 0; mi < 4; ++mi)                                            \
      _Pragma("unroll")                                                       \
      for (int ni = 0; ni < 4; ++ni)                                          \
        acc[(MH) * 4 + mi][ni] = __builtin_amdgcn_mfma_i32_16x16x64_i8(       \
            afr[mi], bfr[ni], acc[(MH) * 4 + mi][ni], 0, 0, 0);               \
    __builtin_amdgcn_s_setprio(0);                                            \
  } while (0)

  // prologue: 6 granules in flight; vmcnt(8) retires g0,g1; barrier publishes.
  STAGE(0); STAGE(1); STAGE(2); STAGE(3); STAGE(4); STAGE(5);
  VMCNT(8); BAR();

#pragma unroll 2
  for (int t = 0; t < 14; ++t) {
    READS(t, 0, 0); STAGE(4 * t + 6); VMCNT(8); BAR(); MFMA16(0); BAR();
    READS(t, 0, 1); STAGE(4 * t + 7); VMCNT(8); BAR(); MFMA16(1); BAR();
    READS(t, 1, 0); STAGE(4 * t + 8); VMCNT(8); BAR(); MFMA16(0); BAR();
    READS(t, 1, 1); STAGE(4 * t + 9); VMCNT(8); BAR(); MFMA16(1); BAR();
  }
  // t=14: last two stages (g62,g63), then drain.
  READS(14, 0, 0); STAGE(62); VMCNT(8); BAR(); MFMA16(0); BAR();
  READS(14, 0, 1); STAGE(63); VMCNT(8); BAR(); MFMA16(1); BAR();
  READS(14, 1, 0);            /* 8 loads out */ BAR(); MFMA16(0); BAR();
  READS(14, 1, 1); VMCNT(4);  /* g60,61 land */ BAR(); MFMA16(1); BAR();
  // t=15
  READS(15, 0, 0);                              BAR(); MFMA16(0); BAR();
  READS(15, 0, 1); VMCNT(0);  /* g62,63 land */ BAR(); MFMA16(1); BAR();
  READS(15, 1, 0); MFMA16(0);                   // no landings remain:
  READS(15, 1, 1); MFMA16(1);                   // barrier-free tail

#undef STAGE
#undef VMCNT
#undef BAR
#undef READS
#undef MFMA16

  // epilogue; C/D layout: col = lane&15, row = (lane>>4)*4 + reg [m89-verified]
  // Nontemporal stores: the 256MB out-stream must not evict A panels from L3
  // (R1: FETCH_SIZE 271MB ~= 4x A re-fetch from HBM).
  const long cm0 = bm + wm * 128;
  const int  cn0 = bn + wn * 64;
  float amv[8][4];
#pragma unroll
  for (int mi = 0; mi < 8; ++mi)
#pragma unroll
    for (int r = 0; r < 4; ++r)
      amv[mi][r] = Am[cm0 + mi * 16 + fq * 4 + r];
#pragma unroll
  for (int ni = 0; ni < 4; ++ni) {
    const int col = cn0 + ni * 16 + fr;
    const float wmv = Bm[col];
    const _Float16 bsv = (_Float16)bias[col];
#pragma unroll
    for (int mi = 0; mi < 8; ++mi) {
#pragma unroll
      for (int r = 0; r < 4; ++r) {
        const long row = cm0 + mi * 16 + fq * 4 + r;
        // mx = fp16(x_max * w_max), promoted to fp32
        const float mx = (float)(_Float16)((_Float16)amv[mi][r] * (_Float16)wmv);
        // res = fp16(res_q_f32 * mx); res = res + bias (fp16 add)
        const _Float16 resh = (_Float16)((float)acc[mi][ni][r] * mx);
        __builtin_nontemporal_store((float)(_Float16)(resh + bsv),
                                    out + row * N_OUT + col);
      }
    }
  }
}

extern "C" void kernel_launch(void* const* d_in, const int* in_sizes, int n_in,
                              void* d_out, int out_size, void* d_ws, size_t ws_size,
                              hipStream_t stream) {
  const float* x      = (const float*)d_in[0];  // [8,4096,2048] fp32 (fp16 values)
  const float* ori_w  = (const float*)d_in[1];  // [2048,2048]
  const float* scales = (const float*)d_in[2];  // [2048]
  const float* bias   = (const float*)d_in[3];  // [2048]
  float* out = (float*)d_out;                   // [8,4096,2048] fp32

  // workspace layout: xq (64MB) | wq (4MB) | xm (128KB fp32) | wm (8KB fp32)
  int8_t* xq = (int8_t*)d_ws;
  int8_t* wq = xq + (size_t)M_TOT * K_IN;
  float*  xm = (float*)(wq + (size_t)N_OUT * K_IN);
  float*  wmx = xm + M_TOT;

  // wave-per-row quant: 4 rows/block; grid-stride for x.
  quant_rows_wave<<<2048, 256, 0, stream>>>(x, scales, xq, xm, M_TOT, 0);
  quant_rows_wave<<<512,  256, 0, stream>>>(ori_w, scales, wq, wmx, N_OUT, 1);

  // 1024 blocks: bid&7 = N-tile (XCD-affine), bid>>3 = M-tile
  gemm_i8_kernel<<<dim3(1024), 512, 0, stream>>>(xq, wq, xm, wmx, bias, out);
}

// Round 4
// 583.077 us; speedup vs baseline: 1.0907x; 1.0082x over previous
//
#include <hip/hip_runtime.h>
#include <hip/hip_bf16.h>
#include <cstdint>
#include <cstddef>

// Problem constants (from reference setup_inputs): B=8, S=4096, IN=OUT=2048
#define M_TOT 32768   // B*S
#define N_OUT 2048
#define K_IN  2048

typedef int   v4i __attribute__((ext_vector_type(4)));
typedef float v4f __attribute__((ext_vector_type(4)));

// async global->LDS, 16B per lane; lds base must be wave-uniform
__device__ __forceinline__ void gload16(const int8_t* g, int8_t* l) {
  __builtin_amdgcn_global_load_lds(
      (const __attribute__((address_space(1))) void*)g,
      (__attribute__((address_space(3))) void*)l, 16, 0, 0);
}

// ---------------------------------------------------------------------------
// Quant: one WAVE per row (2048 elems = 32/lane), shfl-only reduction.
// (unchanged from R2 passing version)
// ---------------------------------------------------------------------------
__global__ __launch_bounds__(256) void quant_rows_wave(
    const float* __restrict__ in,
    const float* __restrict__ scales,
    int8_t* __restrict__ q, float* __restrict__ rmax,
    int nrows, int mul_mode)
{
  const int wib = threadIdx.x >> 6, lane = threadIdx.x & 63;
  for (int row = blockIdx.x * 4 + wib; row < nrows; row += gridDim.x * 4) {
    const float* rp = in + (size_t)row * K_IN;
    _Float16 xs[32];
    float amax = 0.f;
#pragma unroll
    for (int c = 0; c < 8; ++c) {
      const int off = c * 256 + lane * 4;
      const v4f xv = __builtin_nontemporal_load((const v4f*)(rp + off));
      const v4f sv = *(const v4f*)(scales + off);
#pragma unroll
      for (int j = 0; j < 4; ++j) {
        const _Float16 hx = (_Float16)xv[j];
        const _Float16 hs = (_Float16)sv[j];
        const _Float16 v = mul_mode ? (_Float16)(hx * hs) : (_Float16)(hx / hs);
        xs[c * 4 + j] = v;
        amax = fmaxf(amax, fabsf((float)v));
      }
    }
#pragma unroll
    for (int off = 32; off; off >>= 1) amax = fmaxf(amax, __shfl_xor(amax, off));
    _Float16 hqm = (_Float16)amax / (_Float16)127.0f;   // fp16 division
    if (lane == 0) rmax[row] = (float)hqm;
    if (hqm == (_Float16)0.f) hqm = (_Float16)1.0f;     // defensive 0/0 guard
#pragma unroll
    for (int c = 0; c < 8; ++c) {
      int8_t qb[4];
#pragma unroll
      for (int j = 0; j < 4; ++j) {
        const float qf = (float)(_Float16)(xs[c * 4 + j] / hqm);  // fp16 div
        qb[j] = (int8_t)(int)qf;                                  // trunc
      }
      int pk;
      __builtin_memcpy(&pk, qb, 4);
      *(int*)(q + (size_t)row * K_IN + c * 256 + lane * 4) = pk;
    }
  }
}

// ---------------------------------------------------------------------------
// Kernel 3: int8 GEMM, 256x256 tile. R3: MERGED-REGION schedule.
//
// R2 post-mortem: two-barrier phase split serialized LDS-read regions against
// MFMA regions CU-wide (MfmaUtil 37->33). R3 returns to the R1 skeleton
// (reads+MFMA in ONE post-barrier region, compiler-interleaved via fine
// lgkmcnt) and doubles the region size: one region = one (tile, k-half) =
// all 12 fragment reads (8 A + 4 B ds_read_b128) + 32 MFMA (~1300 cyc/SIMD
// at 2 waves) -> read latency amortized 2x, barriers halved (64 -> 32).
//
// Pipeline: region q (q=0..31) covers granules {2q, 2q+1}; stages granules
// {2q+4, 2q+5}; VMCNT(4) once per region -> granules <= 2q+3 landed (2
// granules of slack, ~1 region of runway > 900cyc HBM latency).
// Ring: 8 slots x 16KB. Invariants (re-derived):
//   - reads at q touch {2q,2q+1}; vmcnt at q-1 guaranteed <= 2q+1 ✓
//   - STAGE(2q+4)/(2q+5) overwrite granules 2q-4/2q-3, last read in region
//     q-2 -> separated from the overwrite by barrier q-1 ✓ (cross-wave safe)
//   - publish: per-wave VMCNT precedes BAR(q) which precedes all reads ✓
// Tail: stages end at granule 63 (q=29); q=30 VMCNT(4), q=31 VMCNT(0).
//
// Swizzle (T2, both sides): 16B chunk c of row r stored at chunk c^((r>>1)&3);
// applied to per-lane GLOBAL source at staging (global_load_lds dest must be
// linear) and to the ds_read offset. Bank-conflict-free (measured 0).
// ---------------------------------------------------------------------------
__global__ __launch_bounds__(512, 2) void gemm_i8_kernel(
    const int8_t* __restrict__ Aq, const int8_t* __restrict__ Bq,
    const float* __restrict__ Am, const float* __restrict__ Bm,
    const float* __restrict__ bias, float* __restrict__ out)
{
  __shared__ __align__(16) int8_t lds[8 * 16384];   // 128 KiB ring
  const int tid = threadIdx.x;
  const int w = tid >> 6, lane = tid & 63;
  const int wm = w >> 2, wn = w & 3;                // 2 x 4 wave grid
  // XCD affinity: bid%8 = XCD -> each XCD owns one 256-wide N-panel (B slice
  // 512KB L2-resident); all XCDs sweep the same M-panels (A served by L3).
  const int bx = blockIdx.x & 7;                    // N-tile
  const int by = blockIdx.x >> 3;                   // M-tile
  const long bm = (long)by * 256;
  const int  bn = bx * 256;

  // --- staging source (per thread), inverse-swizzled chunk ---
  const int schunk = ((lane & 3) ^ ((lane >> 3) & 3)) * 16;
  const int srow = w * 16 + (lane >> 2);            // + 128 for 2nd load
  const int8_t* gA = Aq + (bm + srow) * (long)K_IN + schunk;
  const int8_t* gB = Bq + ((long)(bn + srow)) * K_IN + schunk;

  // --- fragment read offsets (swizzled) ---
  const int fr = lane & 15, fq = lane >> 4;
  const int pc = (fq ^ ((fr >> 1) & 3)) * 16;       // physical 16B chunk
  const int aoff = (wm * 128 + fr) * 64 + pc;       // + mi8*16*64
  const int boff = (wn * 64  + fr) * 64 + pc;       // + ni*16*64

  v4i acc[8][4] = {};

  // granule g: tile t=g>>2; g&1: 0=A,1=B; k-half=(g>>1)&1; slot g&7.
#define STAGE(G) do {                                                         \
    const int g_ = (G);                                                       \
    const long koff_ = (long)((g_ >> 2) * 128 + ((g_ >> 1) & 1) * 64);        \
    int8_t* const ld_ = lds + (g_ & 7) * 16384 + w * 1024;                    \
    const int8_t* const gp_ = (g_ & 1) ? gB : gA;                             \
    gload16(gp_ + koff_,                  ld_);                               \
    gload16(gp_ + koff_ + 128L * K_IN,    ld_ + 8192);                        \
  } while (0)

#define VMCNT(N) asm volatile("s_waitcnt vmcnt(" #N ")" ::: "memory")
#define BAR() do { asm volatile("" ::: "memory");                             \
                   __builtin_amdgcn_s_barrier();                              \
                   asm volatile("" ::: "memory"); } while (0)

  // One merged region: 12 ds_read_b128 + 32 MFMA, compiler-interleaved.
#define REGION(T, KH) do {                                                    \
    const int sa_ = (((T) & 1) * 4 + (KH) * 2) * 16384;                       \
    v4i afr[8], bfr[4];                                                       \
    _Pragma("unroll")                                                         \
    for (int ni = 0; ni < 4; ++ni)                                            \
      bfr[ni] = *(const v4i*)(lds + sa_ + 16384 + boff + ni * 1024);          \
    _Pragma("unroll")                                                         \
    for (int mi = 0; mi < 8; ++mi)                                            \
      afr[mi] = *(const v4i*)(lds + sa_ + aoff + mi * 1024);                  \
    __builtin_amdgcn_s_setprio(1);                                            \
    _Pragma("unroll")                                                         \
    for (int mi = 0; mi < 8; ++mi)                                            \
      _Pragma("unroll")                                                       \
      for (int ni = 0; ni < 4; ++ni)                                          \
        acc[mi][ni] = __builtin_amdgcn_mfma_i32_16x16x64_i8(                  \
            afr[mi], bfr[ni], acc[mi][ni], 0, 0, 0);                          \
    __builtin_amdgcn_s_setprio(0);                                            \
  } while (0)

  // prologue: granules 0..3 in flight (8 loads)
  STAGE(0); STAGE(1); STAGE(2); STAGE(3);

#pragma unroll 2
  for (int t = 0; t < 14; ++t) {
    STAGE(4 * t + 4); STAGE(4 * t + 5); VMCNT(4); BAR(); REGION(t, 0);
    STAGE(4 * t + 6); STAGE(4 * t + 7); VMCNT(4); BAR(); REGION(t, 1);
  }
  // t=14: last stages (g60..g63)
  STAGE(60); STAGE(61); VMCNT(4); BAR(); REGION(14, 0);
  STAGE(62); STAGE(63); VMCNT(4); BAR(); REGION(14, 1);
  // t=15: drain
  VMCNT(4); BAR(); REGION(15, 0);
  VMCNT(0); BAR(); REGION(15, 1);

#undef STAGE
#undef VMCNT
#undef BAR
#undef REGION

  // epilogue; C/D layout: col = lane&15, row = (lane>>4)*4 + reg [m89-verified]
  // Nontemporal stores: keep the 256MB out-stream from evicting A in L3.
  const long cm0 = bm + wm * 128;
  const int  cn0 = bn + wn * 64;
  float amv[8][4];
#pragma unroll
  for (int mi = 0; mi < 8; ++mi)
#pragma unroll
    for (int r = 0; r < 4; ++r)
      amv[mi][r] = Am[cm0 + mi * 16 + fq * 4 + r];
#pragma unroll
  for (int ni = 0; ni < 4; ++ni) {
    const int col = cn0 + ni * 16 + fr;
    const float wmv = Bm[col];
    const _Float16 bsv = (_Float16)bias[col];
#pragma unroll
    for (int mi = 0; mi < 8; ++mi) {
#pragma unroll
      for (int r = 0; r < 4; ++r) {
        const long row = cm0 + mi * 16 + fq * 4 + r;
        // mx = fp16(x_max * w_max), promoted to fp32
        const float mx = (float)(_Float16)((_Float16)amv[mi][r] * (_Float16)wmv);
        // res = fp16(res_q_f32 * mx); res = res + bias (fp16 add)
        const _Float16 resh = (_Float16)((float)acc[mi][ni][r] * mx);
        __builtin_nontemporal_store((float)(_Float16)(resh + bsv),
                                    out + row * N_OUT + col);
      }
    }
  }
}

extern "C" void kernel_launch(void* const* d_in, const int* in_sizes, int n_in,
                              void* d_out, int out_size, void* d_ws, size_t ws_size,
                              hipStream_t stream) {
  const float* x      = (const float*)d_in[0];  // [8,4096,2048] fp32 (fp16 values)
  const float* ori_w  = (const float*)d_in[1];  // [2048,2048]
  const float* scales = (const float*)d_in[2];  // [2048]
  const float* bias   = (const float*)d_in[3];  // [2048]
  float* out = (float*)d_out;                   // [8,4096,2048] fp32

  // workspace layout: xq (64MB) | wq (4MB) | xm (128KB fp32) | wm (8KB fp32)
  int8_t* xq = (int8_t*)d_ws;
  int8_t* wq = xq + (size_t)M_TOT * K_IN;
  float*  xm = (float*)(wq + (size_t)N_OUT * K_IN);
  float*  wmx = xm + M_TOT;

  // wave-per-row quant: 4 rows/block; grid-stride for x.
  quant_rows_wave<<<2048, 256, 0, stream>>>(x, scales, xq, xm, M_TOT, 0);
  quant_rows_wave<<<512,  256, 0, stream>>>(ori_w, scales, wq, wmx, N_OUT, 1);

  // 1024 blocks: bid&7 = N-tile (XCD-affine), bid>>3 = M-tile
  gemm_i8_kernel<<<dim3(1024), 512, 0, stream>>>(xq, wq, xm, wmx, bias, out);
}

// Round 5
// 571.487 us; speedup vs baseline: 1.1128x; 1.0203x over previous
//
#include <hip/hip_runtime.h>
#include <hip/hip_bf16.h>
#include <cstdint>
#include <cstddef>

// Problem constants (from reference setup_inputs): B=8, S=4096, IN=OUT=2048
#define M_TOT 32768   // B*S
#define N_OUT 2048
#define K_IN  2048

typedef int   v4i __attribute__((ext_vector_type(4)));
typedef float v4f __attribute__((ext_vector_type(4)));

// async global->LDS, 16B per lane; lds base must be wave-uniform
__device__ __forceinline__ void gload16(const int8_t* g, int8_t* l) {
  __builtin_amdgcn_global_load_lds(
      (const __attribute__((address_space(1))) void*)g,
      (__attribute__((address_space(3))) void*)l, 16, 0, 0);
}

// ---------------------------------------------------------------------------
// Quant: one WAVE per row (2048 elems = 32/lane), shfl-only reduction.
// (unchanged from R2/R4 passing version)
// ---------------------------------------------------------------------------
__global__ __launch_bounds__(256) void quant_rows_wave(
    const float* __restrict__ in,
    const float* __restrict__ scales,
    int8_t* __restrict__ q, float* __restrict__ rmax,
    int nrows, int mul_mode)
{
  const int wib = threadIdx.x >> 6, lane = threadIdx.x & 63;
  for (int row = blockIdx.x * 4 + wib; row < nrows; row += gridDim.x * 4) {
    const float* rp = in + (size_t)row * K_IN;
    _Float16 xs[32];
    float amax = 0.f;
#pragma unroll
    for (int c = 0; c < 8; ++c) {
      const int off = c * 256 + lane * 4;
      const v4f xv = __builtin_nontemporal_load((const v4f*)(rp + off));
      const v4f sv = *(const v4f*)(scales + off);
#pragma unroll
      for (int j = 0; j < 4; ++j) {
        const _Float16 hx = (_Float16)xv[j];
        const _Float16 hs = (_Float16)sv[j];
        const _Float16 v = mul_mode ? (_Float16)(hx * hs) : (_Float16)(hx / hs);
        xs[c * 4 + j] = v;
        amax = fmaxf(amax, fabsf((float)v));
      }
    }
#pragma unroll
    for (int off = 32; off; off >>= 1) amax = fmaxf(amax, __shfl_xor(amax, off));
    _Float16 hqm = (_Float16)amax / (_Float16)127.0f;   // fp16 division
    if (lane == 0) rmax[row] = (float)hqm;
    if (hqm == (_Float16)0.f) hqm = (_Float16)1.0f;     // defensive 0/0 guard
#pragma unroll
    for (int c = 0; c < 8; ++c) {
      int8_t qb[4];
#pragma unroll
      for (int j = 0; j < 4; ++j) {
        const float qf = (float)(_Float16)(xs[c * 4 + j] / hqm);  // fp16 div
        qb[j] = (int8_t)(int)qf;                                  // trunc
      }
      int pk;
      __builtin_memcpy(&pk, qb, 4);
      *(int*)(q + (size_t)row * K_IN + c * 256 + lane * 4) = pk;
    }
  }
}

// ---------------------------------------------------------------------------
// Kernel 3: int8 GEMM, 256x256 tile, merged-region schedule (R3/R4 structure,
// unchanged). R5 changes ONLY the block->tile swizzle:
//
// R4 swizzle (bx = bid&7) spread the 8 blocks sharing one A-panel across 8
// XCDs -> 8 private-L2 fills per panel, and per-XCD all co-resident blocks
// had DISTINCT A panels -> zero L2 reuse of A (FETCH 271MB ~= 4x A).
// R5: each XCD owns a contiguous M-range; the 8 N-blocks of one A-panel are
// co-resident ON THE SAME XCD -> panel fetched once per L2, 8-way shared.
//   xcd = bid&7; r = bid>>3; bx = r&7; by = xcd*16 + (r>>3)
// Co-resident per XCD (32 blocks) = 4 by x 8 bx: A ws 2MB (8 sharers each),
// B ws 4MB (4 sharers + cross-round reuse). Discriminator: if FETCH stays
// ~271MB the over-fetch is out-stream RFO, not A (next lever: store
// coalescing via LDS-transpose epilogue).
//
// Pipeline (unchanged): region q reads granules {2q,2q+1}; stages {2q+4,
// 2q+5}; VMCNT(4) once per region; 8-slot 16KB ring; invariants as R3.
// Swizzle T2 (unchanged): chunk c of row r at c^((r>>1)&3), both sides.
// ---------------------------------------------------------------------------
__global__ __launch_bounds__(512, 2) void gemm_i8_kernel(
    const int8_t* __restrict__ Aq, const int8_t* __restrict__ Bq,
    const float* __restrict__ Am, const float* __restrict__ Bm,
    const float* __restrict__ bias, float* __restrict__ out)
{
  __shared__ __align__(16) int8_t lds[8 * 16384];   // 128 KiB ring
  const int tid = threadIdx.x;
  const int w = tid >> 6, lane = tid & 63;
  const int wm = w >> 2, wn = w & 3;                // 2 x 4 wave grid
  // --- R5 swizzle: XCD owns M-panels; A-panel sharers co-resident per XCD ---
  const int xcd = blockIdx.x & 7;
  const int r   = blockIdx.x >> 3;
  const int bx  = r & 7;                            // N-tile
  const int by  = xcd * 16 + (r >> 3);              // M-tile (XCD-affine)
  const long bm = (long)by * 256;
  const int  bn = bx * 256;

  // --- staging source (per thread), inverse-swizzled chunk ---
  const int schunk = ((lane & 3) ^ ((lane >> 3) & 3)) * 16;
  const int srow = w * 16 + (lane >> 2);            // + 128 for 2nd load
  const int8_t* gA = Aq + (bm + srow) * (long)K_IN + schunk;
  const int8_t* gB = Bq + ((long)(bn + srow)) * K_IN + schunk;

  // --- fragment read offsets (swizzled) ---
  const int fr = lane & 15, fq = lane >> 4;
  const int pc = (fq ^ ((fr >> 1) & 3)) * 16;       // physical 16B chunk
  const int aoff = (wm * 128 + fr) * 64 + pc;       // + mi8*16*64
  const int boff = (wn * 64  + fr) * 64 + pc;       // + ni*16*64

  v4i acc[8][4] = {};

  // granule g: tile t=g>>2; g&1: 0=A,1=B; k-half=(g>>1)&1; slot g&7.
#define STAGE(G) do {                                                         \
    const int g_ = (G);                                                       \
    const long koff_ = (long)((g_ >> 2) * 128 + ((g_ >> 1) & 1) * 64);        \
    int8_t* const ld_ = lds + (g_ & 7) * 16384 + w * 1024;                    \
    const int8_t* const gp_ = (g_ & 1) ? gB : gA;                             \
    gload16(gp_ + koff_,                  ld_);                               \
    gload16(gp_ + koff_ + 128L * K_IN,    ld_ + 8192);                        \
  } while (0)

#define VMCNT(N) asm volatile("s_waitcnt vmcnt(" #N ")" ::: "memory")
#define BAR() do { asm volatile("" ::: "memory");                             \
                   __builtin_amdgcn_s_barrier();                              \
                   asm volatile("" ::: "memory"); } while (0)

  // One merged region: 12 ds_read_b128 + 32 MFMA, compiler-interleaved.
#define REGION(T, KH) do {                                                    \
    const int sa_ = (((T) & 1) * 4 + (KH) * 2) * 16384;                       \
    v4i afr[8], bfr[4];                                                       \
    _Pragma("unroll")                                                         \
    for (int ni = 0; ni < 4; ++ni)                                            \
      bfr[ni] = *(const v4i*)(lds + sa_ + 16384 + boff + ni * 1024);          \
    _Pragma("unroll")                                                         \
    for (int mi = 0; mi < 8; ++mi)                                            \
      afr[mi] = *(const v4i*)(lds + sa_ + aoff + mi * 1024);                  \
    __builtin_amdgcn_s_setprio(1);                                            \
    _Pragma("unroll")                                                         \
    for (int mi = 0; mi < 8; ++mi)                                            \
      _Pragma("unroll")                                                       \
      for (int ni = 0; ni < 4; ++ni)                                          \
        acc[mi][ni] = __builtin_amdgcn_mfma_i32_16x16x64_i8(                  \
            afr[mi], bfr[ni], acc[mi][ni], 0, 0, 0);                          \
    __builtin_amdgcn_s_setprio(0);                                            \
  } while (0)

  // prologue: granules 0..3 in flight (8 loads)
  STAGE(0); STAGE(1); STAGE(2); STAGE(3);

#pragma unroll 2
  for (int t = 0; t < 14; ++t) {
    STAGE(4 * t + 4); STAGE(4 * t + 5); VMCNT(4); BAR(); REGION(t, 0);
    STAGE(4 * t + 6); STAGE(4 * t + 7); VMCNT(4); BAR(); REGION(t, 1);
  }
  // t=14: last stages (g60..g63)
  STAGE(60); STAGE(61); VMCNT(4); BAR(); REGION(14, 0);
  STAGE(62); STAGE(63); VMCNT(4); BAR(); REGION(14, 1);
  // t=15: drain
  VMCNT(4); BAR(); REGION(15, 0);
  VMCNT(0); BAR(); REGION(15, 1);

#undef STAGE
#undef VMCNT
#undef BAR
#undef REGION

  // epilogue; C/D layout: col = lane&15, row = (lane>>4)*4 + reg [m89-verified]
  const long cm0 = bm + wm * 128;
  const int  cn0 = bn + wn * 64;
  float amv[8][4];
#pragma unroll
  for (int mi = 0; mi < 8; ++mi)
#pragma unroll
    for (int r2 = 0; r2 < 4; ++r2)
      amv[mi][r2] = Am[cm0 + mi * 16 + fq * 4 + r2];
#pragma unroll
  for (int ni = 0; ni < 4; ++ni) {
    const int col = cn0 + ni * 16 + fr;
    const float wmv = Bm[col];
    const _Float16 bsv = (_Float16)bias[col];
#pragma unroll
    for (int mi = 0; mi < 8; ++mi) {
#pragma unroll
      for (int r2 = 0; r2 < 4; ++r2) {
        const long row = cm0 + mi * 16 + fq * 4 + r2;
        // mx = fp16(x_max * w_max), promoted to fp32
        const float mx = (float)(_Float16)((_Float16)amv[mi][r2] * (_Float16)wmv);
        // res = fp16(res_q_f32 * mx); res = res + bias (fp16 add)
        const _Float16 resh = (_Float16)((float)acc[mi][ni][r2] * mx);
        __builtin_nontemporal_store((float)(_Float16)(resh + bsv),
                                    out + row * N_OUT + col);
      }
    }
  }
}

extern "C" void kernel_launch(void* const* d_in, const int* in_sizes, int n_in,
                              void* d_out, int out_size, void* d_ws, size_t ws_size,
                              hipStream_t stream) {
  const float* x      = (const float*)d_in[0];  // [8,4096,2048] fp32 (fp16 values)
  const float* ori_w  = (const float*)d_in[1];  // [2048,2048]
  const float* scales = (const float*)d_in[2];  // [2048]
  const float* bias   = (const float*)d_in[3];  // [2048]
  float* out = (float*)d_out;                   // [8,4096,2048] fp32

  // workspace layout: xq (64MB) | wq (4MB) | xm (128KB fp32) | wm (8KB fp32)
  int8_t* xq = (int8_t*)d_ws;
  int8_t* wq = xq + (size_t)M_TOT * K_IN;
  float*  xm = (float*)(wq + (size_t)N_OUT * K_IN);
  float*  wmx = xm + M_TOT;

  // wave-per-row quant: 4 rows/block; grid-stride for x.
  quant_rows_wave<<<2048, 256, 0, stream>>>(x, scales, xq, xm, M_TOT, 0);
  quant_rows_wave<<<512,  256, 0, stream>>>(ori_w, scales, wq, wmx, N_OUT, 1);

  // 1024 blocks: xcd = bid&7 owns M-panels [16*xcd, 16*xcd+16); bx = (bid>>3)&7
  gemm_i8_kernel<<<dim3(1024), 512, 0, stream>>>(xq, wq, xm, wmx, bias, out);
}